// Round 1
// 837.036 us; speedup vs baseline: 1.2984x; 1.2984x over previous
//
#include <hip/hip_runtime.h>
#include <math.h>

#define HW       65536     // 256*256
#define NCH      64        // C
#define HIDDEN   128
#define NBATCH   32
#define NPIX     (NBATCH * HW)   // 2,097,152
#define WIN      2048            // pixels per K1 block
#define NBLK     (NPIX / WIN)    // 1024 blocks
#define WPB      (HW / WIN)      // 32 windows per batch
#define NEG_FILL -1e9f

// -------------------------------------------------------------------------
// Kernel 1: mask-compacted per-pixel MLP.
// Each block owns a 2048-pixel window of one batch. It ballot-compacts the
// ~11% masked pixels into an LDS list, gathers only their 64 channels, and
// runs the register-tiled fp32 GEMM on 64-pixel compacted tiles.
// Also produces per-block softmax partials (max, sum-exp) -> no stats pass.
// LDS: sW 32K + sFc 16K + sfull 8K + slist 4K ~= 60.5 KB (2 blocks/CU).
// -------------------------------------------------------------------------
__global__ __launch_bounds__(256, 2) void mask_mlp_kernel(
    const float* __restrict__ feat,   // (B, C, H, W)
    const float* __restrict__ W1,     // (HIDDEN, C) row-major
    const float* __restrict__ b1,     // (HIDDEN)
    const float* __restrict__ W2,     // (HIDDEN)
    const float* __restrict__ b2,     // scalar
    const int*   __restrict__ zone,   // (B, H, W)
    const int*   __restrict__ cats,   // (B)
    float*       __restrict__ att,    // (B, H, W) out: masked scores
    float*       __restrict__ pmax,   // (NBLK) per-block max
    float*       __restrict__ psum)   // (NBLK) per-block sum exp(x - max)
{
    __shared__ __align__(16) float sW[NCH][HIDDEN];      // sW[c][k] = W1[k][c]
    __shared__ __align__(16) float sFc[NCH][64];         // compacted feature tile
    __shared__ __align__(16) float sfull[WIN];           // window scores
    __shared__ unsigned short slist[WIN];                // compacted local px idx
    __shared__ float sred[8];
    __shared__ int lcnt;

    const int tid  = threadIdx.x;
    const int lane = tid & 63;
    const int wid  = tid >> 6;
    const int b    = blockIdx.x >> 5;             // WPB == 32
    const int win0 = (blockIdx.x & 31) * WIN;

    if (tid == 0) lcnt = 0;
    __syncthreads();

    // ---- stage W1 transposed (lanes walk k: conflict-free LDS stores) ----
    #pragma unroll
    for (int r = 0; r < 8; ++r) {
        int idx = tid + r * 256;      // 0..2047
        int k   = idx & 127;
        int c4  = idx >> 7;           // 0..15
        float4 v = *(const float4*)(W1 + k * NCH + c4 * 4);
        sW[c4 * 4 + 0][k] = v.x;
        sW[c4 * 4 + 1][k] = v.y;
        sW[c4 * 4 + 2][k] = v.z;
        sW[c4 * 4 + 3][k] = v.w;
    }

    // ---- init window scores to NEG_FILL ----
    {
        float4 nf = make_float4(NEG_FILL, NEG_FILL, NEG_FILL, NEG_FILL);
        *(float4*)&sfull[tid * 4]         = nf;
        *(float4*)&sfull[(tid + 256) * 4] = nf;
    }

    // ---- scan zone, ballot-compact masked pixels (order within a wave-
    //      group is ascending -> gather lanes hit near-consecutive lines) ----
    {
        const int  catb = cats[b];
        const int* zp   = zone + (size_t)b * HW + win0;
        #pragma unroll
        for (int j = 0; j < 8; ++j) {
            int  px = j * 256 + tid;          // lanes -> consecutive pixels
            int  z  = zp[px];
            bool m  = (z == catb) && (z > 0);
            unsigned long long bal = __ballot(m);
            int rank = __popcll(bal & ((1ull << lane) - 1ull));
            int base = 0;
            if (lane == 0) {
                int cnt = __popcll(bal);
                if (cnt) base = atomicAdd(&lcnt, cnt);
            }
            base = __shfl(base, 0, 64);
            if (m) slist[base + rank] = (unsigned short)px;
        }
    }
    __syncthreads();

    const int n  = lcnt;                 // masked pixels in this window (~228)
    const int nt = (n + 63) >> 6;        // 64-pixel compacted tiles

    const int tx = tid & 15;             // hidden group: k = tx*4+j / 64+tx*4+j
    const int ty = tid >> 4;             // pixel group:  p = ty*4+i

    float b1v[8], w2v[8];
    *(float4*)&b1v[0] = *(const float4*)(b1 + tx * 4);
    *(float4*)&b1v[4] = *(const float4*)(b1 + 64 + tx * 4);
    *(float4*)&w2v[0] = *(const float4*)(W2 + tx * 4);
    *(float4*)&w2v[4] = *(const float4*)(W2 + 64 + tx * 4);
    const float b2v = b2[0];

    const float* fb = feat + (size_t)b * NCH * HW + win0;

    for (int t = 0; t < nt; ++t) {
        // ---- gather: wave w loads channels w*16..w*16+15 for 64 slots ----
        {
            int  p     = tid & 63;
            int  cw    = tid >> 6;
            int  slot  = t * 64 + p;
            bool valid = slot < n;
            int  lpx   = valid ? (int)slist[slot] : 0;
            const float* fp = fb + lpx;
            #pragma unroll
            for (int cc = 0; cc < 16; ++cc) {
                int c = cw * 16 + cc;
                float v = 0.f;
                if (valid) v = fp[(size_t)c * HW];
                sFc[c][p] = v;            // lanes consecutive p: conflict-free
            }
        }
        __syncthreads();

        // ---- 64px x 128hid x 64c register-tiled GEMM ----
        float acc[4][8];
        #pragma unroll
        for (int i = 0; i < 4; ++i)
            #pragma unroll
            for (int j = 0; j < 8; ++j) acc[i][j] = 0.f;

        #pragma unroll 8
        for (int c = 0; c < NCH; ++c) {
            float a[4], w[8];
            *(float4*)&a[0] = *(const float4*)&sFc[c][ty * 4];       // broadcast groups
            *(float4*)&w[0] = *(const float4*)&sW[c][tx * 4];        // 2-way (free)
            *(float4*)&w[4] = *(const float4*)&sW[c][64 + tx * 4];   // 2-way (free)
            #pragma unroll
            for (int i = 0; i < 4; ++i)
                #pragma unroll
                for (int j = 0; j < 8; ++j)
                    acc[i][j] = fmaf(a[i], w[j], acc[i][j]);
        }

        // ---- epilogue: relu + W2 dot, reduce across the 16 tx lanes ----
        #pragma unroll
        for (int i = 0; i < 4; ++i) {
            float s = 0.f;
            #pragma unroll
            for (int j = 0; j < 8; ++j) {
                float h = acc[i][j] + b1v[j];
                h = h > 0.f ? h : 0.f;
                s = fmaf(w2v[j], h, s);
            }
            s += __shfl_xor(s, 1, 64);
            s += __shfl_xor(s, 2, 64);
            s += __shfl_xor(s, 4, 64);
            s += __shfl_xor(s, 8, 64);
            if (tx == 0) {
                int slot = t * 64 + ty * 4 + i;
                if (slot < n) sfull[slist[slot]] = s + b2v;
            }
        }
        __syncthreads();
    }

    // ---- per-block softmax partials over the window ----
    float4 x0 = *(float4*)&sfull[tid * 8];
    float4 x1 = *(float4*)&sfull[tid * 8 + 4];
    float m = fmaxf(fmaxf(fmaxf(x0.x, x0.y), fmaxf(x0.z, x0.w)),
                    fmaxf(fmaxf(x1.x, x1.y), fmaxf(x1.z, x1.w)));
    #pragma unroll
    for (int k = 1; k < 64; k <<= 1) m = fmaxf(m, __shfl_xor(m, k, 64));
    if (lane == 0) sred[wid] = m;
    __syncthreads();
    const float M = fmaxf(fmaxf(sred[0], sred[1]), fmaxf(sred[2], sred[3]));

    // NEG_FILL entries: expf(-1e9 - M) underflows to exactly 0 (matches ref)
    float es = expf(x0.x - M) + expf(x0.y - M) + expf(x0.z - M) + expf(x0.w - M)
             + expf(x1.x - M) + expf(x1.y - M) + expf(x1.z - M) + expf(x1.w - M);
    #pragma unroll
    for (int k = 1; k < 64; k <<= 1) es += __shfl_xor(es, k, 64);
    if (lane == 0) sred[4 + wid] = es;
    __syncthreads();
    if (tid == 0) {
        pmax[blockIdx.x] = M;
        psum[blockIdx.x] = sred[4] + sred[5] + sred[6] + sred[7];
    }

    // ---- write window scores (att = out+1 is only 4B-aligned: scalar) ----
    float* ap = att + (size_t)b * HW + win0;
    #pragma unroll
    for (int r = 0; r < 8; ++r)
        ap[r * 256 + tid] = sfull[r * 256 + tid];
}

// -------------------------------------------------------------------------
// Kernel 2: merge 32 per-window partials per batch -> (max, sum); init bag.
// Replaces the old 2-pass 16.8 MB stats kernel.
// -------------------------------------------------------------------------
__global__ __launch_bounds__(64) void merge_kernel(
    const float* __restrict__ pmax, const float* __restrict__ psum,
    float* __restrict__ maxv, float* __restrict__ sumv, float* __restrict__ bag)
{
    const int b = blockIdx.x;
    const int t = threadIdx.x;
    float m = -3.4e38f, s = 0.f;
    if (t < WPB) { m = pmax[b * WPB + t]; s = psum[b * WPB + t]; }
    float M = m;
    #pragma unroll
    for (int k = 1; k < 64; k <<= 1) M = fmaxf(M, __shfl_xor(M, k, 64));
    float z = s * expf(m - M);      // inactive lanes: 0 * 0 = 0
    #pragma unroll
    for (int k = 1; k < 64; k <<= 1) z += __shfl_xor(z, k, 64);
    if (t == 0) { maxv[b] = M; sumv[b] = z; bag[b] = 0.f; }
}

// -------------------------------------------------------------------------
// Kernel 3: weights = exp(att-max)/sum (gated by has), bag += logit*weight.
// att buffer (d_out+1) is rewritten in place with the weights.
// -------------------------------------------------------------------------
__global__ __launch_bounds__(256) void finalize_kernel(
    float* __restrict__ att,              // in: scores, out: weights
    const float* __restrict__ logits,     // (B,1,H,W) flat
    const float* __restrict__ maxv, const float* __restrict__ sumv,
    float* __restrict__ bag)
{
    const int idx = blockIdx.x * 256 + threadIdx.x;
    const int b   = idx >> 16;
    const float mx  = maxv[b];
    const bool  has = mx > -5e8f;         // any unmasked pixel?
    const float inv = 1.f / sumv[b];

    const float a = att[idx];
    // masked positions: a == -1e9 -> expf underflows to exactly 0 (matches ref)
    const float w = has ? expf(a - mx) * inv : 0.f;
    att[idx] = w;

    float part = w * logits[idx];
    #pragma unroll
    for (int s = 1; s < 64; s <<= 1) part += __shfl_xor(part, s, 64);
    __shared__ float r[4];
    if ((threadIdx.x & 63) == 0) r[threadIdx.x >> 6] = part;
    __syncthreads();
    if (threadIdx.x == 0) atomicAdd(&bag[b], r[0] + r[1] + r[2] + r[3]);
}

// -------------------------------------------------------------------------
// Kernel 4: BCE-with-logits mean over batch -> d_out[0]
// -------------------------------------------------------------------------
__global__ __launch_bounds__(64) void loss_kernel(
    const float* __restrict__ bag, const float* __restrict__ labels,
    float* __restrict__ out)
{
    const int t = threadIdx.x;
    float l = 0.f;
    if (t < NBATCH) {
        float x = bag[t], y = labels[t];
        l = fmaxf(x, 0.f) - x * y + log1pf(expf(-fabsf(x)));
    }
    #pragma unroll
    for (int s = 1; s < 64; s <<= 1) l += __shfl_xor(l, s, 64);
    if (t == 0) out[0] = l * (1.f / NBATCH);
}

extern "C" void kernel_launch(void* const* d_in, const int* in_sizes, int n_in,
                              void* d_out, int out_size, void* d_ws, size_t ws_size,
                              hipStream_t stream)
{
    const float* logits = (const float*)d_in[0];  // (32,1,256,256)
    const float* feat   = (const float*)d_in[1];  // (32,64,256,256)
    const int*   zone   = (const int*)  d_in[2];  // (32,256,256)
    const int*   cats   = (const int*)  d_in[3];  // (32,)
    const float* labels = (const float*)d_in[4];  // (32,)
    const float* W1     = (const float*)d_in[5];  // (128,64)
    const float* b1v    = (const float*)d_in[6];  // (128,)
    const float* W2     = (const float*)d_in[7];  // (128,)
    const float* b2v    = (const float*)d_in[8];  // scalar

    float* out = (float*)d_out;       // [0] = loss, [1..] = attention_maps
    float* att = out + 1;             // reuse output buffer as score scratch

    float* wsf   = (float*)d_ws;      // 8704 B of stats scratch (ws is poisoned
    float* pmaxb = wsf;               //  each launch; every slot is rewritten)
    float* psumb = wsf + NBLK;        // + 1024
    float* maxv  = wsf + 2 * NBLK;    // + 32
    float* sumv  = maxv + NBATCH;     // + 32
    float* bag   = sumv + NBATCH;     // + 32

    mask_mlp_kernel<<<NBLK, 256, 0, stream>>>(feat, W1, b1v, W2, b2v, zone, cats,
                                              att, pmaxb, psumb);
    merge_kernel   <<<NBATCH, 64, 0, stream>>>(pmaxb, psumb, maxv, sumv, bag);
    finalize_kernel<<<NPIX / 256, 256, 0, stream>>>(att, logits, maxv, sumv, bag);
    loss_kernel    <<<1, 64, 0, stream>>>(bag, labels, out);
}

// Round 2
// 780.461 us; speedup vs baseline: 1.3925x; 1.0725x over previous
//
#include <hip/hip_runtime.h>
#include <math.h>

#define HW       65536     // 256*256
#define NCH      64        // C
#define HIDDEN   128
#define NBATCH   32
#define NPIX     (NBATCH * HW)   // 2,097,152
#define WIN      2048            // pixels per K1 block
#define NBLK     (NPIX / WIN)    // 1024 blocks
#define WPB      (HW / WIN)      // 32 windows per batch
#define NEG_FILL -1e9f

// -------------------------------------------------------------------------
// Kernel 1: mask-compacted per-pixel MLP, online softmax partials.
// Each block owns a 2048-pixel window of one batch. Ballot-compacts the
// ~11% masked pixels, gathers only their 64 channels, runs the register-
// tiled fp32 GEMM on 64-pixel compacted tiles, scatters scores directly to
// att, and tracks per-window (max, sum-exp) online in registers.
// LDS: sW 32K + sFc 16K + slist 4K ~= 52.3 KB -> 3 blocks/CU (12 waves).
// att background (unmasked px) is NEVER written here; finalize re-derives
// the mask from zone and writes 0 there.
// -------------------------------------------------------------------------
__global__ __launch_bounds__(256, 3) void mask_mlp_kernel(
    const float* __restrict__ feat,   // (B, C, H, W)
    const float* __restrict__ W1,     // (HIDDEN, C) row-major
    const float* __restrict__ b1,     // (HIDDEN)
    const float* __restrict__ W2,     // (HIDDEN)
    const float* __restrict__ b2,     // scalar
    const int*   __restrict__ zone,   // (B, H, W)
    const int*   __restrict__ cats,   // (B)
    float*       __restrict__ att,    // (B, H, W) out: scores at masked px only
    float*       __restrict__ pmax,   // (NBLK) per-window max   (-3.4e38 if none)
    float*       __restrict__ psum)   // (NBLK) per-window sum exp(x - max)
{
    __shared__ __align__(16) float sW[NCH][HIDDEN];      // sW[c][k] = W1[k][c]
    __shared__ __align__(16) float sFc[NCH][64];         // compacted feature tile
    __shared__ unsigned short slist[WIN];                // compacted local px idx
    __shared__ float sred[8];
    __shared__ int lcnt;

    const int tid  = threadIdx.x;
    const int lane = tid & 63;
    const int b    = blockIdx.x >> 5;             // WPB == 32
    const int win0 = (blockIdx.x & 31) * WIN;

    if (tid == 0) lcnt = 0;
    __syncthreads();

    // ---- stage W1 transposed (lanes walk k: conflict-free LDS stores) ----
    #pragma unroll
    for (int r = 0; r < 8; ++r) {
        int idx = tid + r * 256;      // 0..2047
        int k   = idx & 127;
        int c4  = idx >> 7;           // 0..15
        float4 v = *(const float4*)(W1 + k * NCH + c4 * 4);
        sW[c4 * 4 + 0][k] = v.x;
        sW[c4 * 4 + 1][k] = v.y;
        sW[c4 * 4 + 2][k] = v.z;
        sW[c4 * 4 + 3][k] = v.w;
    }

    // ---- scan zone, ballot-compact masked pixels (ascending order) ----
    {
        const int  catb = cats[b];
        const int* zp   = zone + (size_t)b * HW + win0;
        #pragma unroll
        for (int j = 0; j < 8; ++j) {
            int  px = j * 256 + tid;          // lanes -> consecutive pixels
            int  z  = zp[px];
            bool m  = (z == catb) && (z > 0);
            unsigned long long bal = __ballot(m);
            int rank = __popcll(bal & ((1ull << lane) - 1ull));
            int base = 0;
            if (lane == 0) {
                int cnt = __popcll(bal);
                if (cnt) base = atomicAdd(&lcnt, cnt);
            }
            base = __shfl(base, 0, 64);
            if (m) slist[base + rank] = (unsigned short)px;
        }
    }
    __syncthreads();

    const int n  = lcnt;                 // masked pixels in this window (~228)
    const int nt = (n + 63) >> 6;        // 64-pixel compacted tiles

    const int tx = tid & 15;             // hidden group: k = tx*4+j / 64+tx*4+j
    const int ty = tid >> 4;             // pixel group:  p = ty*4+i

    float b1v[8], w2v[8];
    *(float4*)&b1v[0] = *(const float4*)(b1 + tx * 4);
    *(float4*)&b1v[4] = *(const float4*)(b1 + 64 + tx * 4);
    *(float4*)&w2v[0] = *(const float4*)(W2 + tx * 4);
    *(float4*)&w2v[4] = *(const float4*)(W2 + 64 + tx * 4);
    const float b2v = b2[0];

    const float* fb = feat + (size_t)b * NCH * HW + win0;
    float*       ap = att  + (size_t)b * HW + win0;

    float mrun = -3.4e38f, srun = 0.f;   // online softmax partials

    for (int t = 0; t < nt; ++t) {
        // ---- gather: wave w loads channels w*16..w*16+15 for 64 slots ----
        {
            int  p     = tid & 63;
            int  cw    = tid >> 6;
            int  slot  = t * 64 + p;
            bool valid = slot < n;
            int  lpx   = valid ? (int)slist[slot] : 0;
            const float* fp = fb + lpx;
            #pragma unroll
            for (int cc = 0; cc < 16; ++cc) {
                int c = cw * 16 + cc;
                float v = 0.f;
                if (valid) v = fp[(size_t)c * HW];
                sFc[c][p] = v;            // lanes consecutive p: conflict-free
            }
        }
        __syncthreads();

        // ---- 64px x 128hid x 64c register-tiled GEMM ----
        float acc[4][8];
        #pragma unroll
        for (int i = 0; i < 4; ++i)
            #pragma unroll
            for (int j = 0; j < 8; ++j) acc[i][j] = 0.f;

        #pragma unroll 8
        for (int c = 0; c < NCH; ++c) {
            float a[4], w[8];
            *(float4*)&a[0] = *(const float4*)&sFc[c][ty * 4];       // broadcast
            *(float4*)&w[0] = *(const float4*)&sW[c][tx * 4];        // 2-way (free)
            *(float4*)&w[4] = *(const float4*)&sW[c][64 + tx * 4];   // 2-way (free)
            #pragma unroll
            for (int i = 0; i < 4; ++i)
                #pragma unroll
                for (int j = 0; j < 8; ++j)
                    acc[i][j] = fmaf(a[i], w[j], acc[i][j]);
        }

        // ---- epilogue: relu + W2 dot, reduce over 16 tx lanes, scatter ----
        #pragma unroll
        for (int i = 0; i < 4; ++i) {
            float s = 0.f;
            #pragma unroll
            for (int j = 0; j < 8; ++j) {
                float h = acc[i][j] + b1v[j];
                h = h > 0.f ? h : 0.f;
                s = fmaf(w2v[j], h, s);
            }
            s += __shfl_xor(s, 1, 64);
            s += __shfl_xor(s, 2, 64);
            s += __shfl_xor(s, 4, 64);
            s += __shfl_xor(s, 8, 64);
            if (tx == 0) {
                int slot = t * 64 + ty * 4 + i;
                if (slot < n) {
                    float v = s + b2v;
                    ap[slist[slot]] = v;                 // scatter score
                    float nm = fmaxf(mrun, v);           // online (m, s) update
                    srun = srun * expf(mrun - nm) + expf(v - nm);
                    mrun = nm;
                }
            }
        }
        __syncthreads();    // sFc consumed; next gather may overwrite
    }

    // ---- block-combine online (m, s) pairs -> per-window partials ----
    {
        float m = mrun, s = srun;
        #pragma unroll
        for (int k = 1; k < 64; k <<= 1) {
            float mo = __shfl_xor(m, k, 64);
            float so = __shfl_xor(s, k, 64);
            float nm = fmaxf(m, mo);
            s = s * expf(m - nm) + so * expf(mo - nm);   // finite sentinel: no NaN
            m = nm;
        }
        if (lane == 0) { sred[tid >> 6] = m; sred[4 + (tid >> 6)] = s; }
    }
    __syncthreads();
    if (tid == 0) {
        float M = sred[0], S = sred[4];
        #pragma unroll
        for (int i = 1; i < 4; ++i) {
            float mo = sred[i], so = sred[4 + i];
            float nm = fmaxf(M, mo);
            S = S * expf(M - nm) + so * expf(mo - nm);
            M = nm;
        }
        pmax[blockIdx.x] = M;
        psum[blockIdx.x] = S;
    }
}

// -------------------------------------------------------------------------
// Kernel 2: finalize. Each block (256 px of one batch) first merges the 32
// per-window partials (cheap, L2-cached), then: mask from zone, weights =
// mask&&has ? exp(score-M)/S : 0, written to att; per-block bag partial to
// pbag[blockIdx.x] -- NO atomics (the old 8192-atomics-to-2-lines serializer).
// Unmasked att entries were never written by K1 (poison); they are selected
// away by the mask ternary, never propagated.
// -------------------------------------------------------------------------
__global__ __launch_bounds__(256) void finalize_kernel(
    float* __restrict__ att,              // in: scores at masked px, out: weights
    const float* __restrict__ logits,     // (B,1,H,W) flat
    const int*   __restrict__ zone,       // (B, H, W)
    const int*   __restrict__ cats,       // (B)
    const float* __restrict__ pmaxb, const float* __restrict__ psumb,
    float* __restrict__ pbag)             // (NPIX/256) per-block bag partials
{
    __shared__ float sM, sInv;
    __shared__ int   sHas;
    __shared__ float r4[4];

    const int bid = blockIdx.x;
    const int b   = bid >> 8;             // 256 blocks per batch
    const int tid = threadIdx.x;

    if (tid < 64) {                       // merge 32 window partials
        float m = -3.4e38f, sv = 0.f;
        if (tid < WPB) { m = pmaxb[b * WPB + tid]; sv = psumb[b * WPB + tid]; }
        float M = m;
        #pragma unroll
        for (int k = 1; k < 64; k <<= 1) M = fmaxf(M, __shfl_xor(M, k, 64));
        float z = sv * expf(m - M);       // empty windows: 0 * exp(-huge) = 0
        #pragma unroll
        for (int k = 1; k < 64; k <<= 1) z += __shfl_xor(z, k, 64);
        if (tid == 0) {
            bool has = M > -5e8f;         // any masked pixel in batch?
            sM   = M;
            sHas = has ? 1 : 0;
            sInv = has ? (1.f / z) : 0.f;
        }
    }
    __syncthreads();

    const float M   = sM;
    const float inv = sInv;
    const bool  has = sHas != 0;

    const int idx  = bid * 256 + tid;
    const int catb = cats[b];
    const int z    = zone[idx];
    const bool mk  = (z == catb) && (z > 0);

    const float a = att[idx];             // garbage at unmasked: selected away
    const float w = (mk && has) ? expf(a - M) * inv : 0.f;
    att[idx] = w;

    float part = w * logits[idx];
    #pragma unroll
    for (int s = 1; s < 64; s <<= 1) part += __shfl_xor(part, s, 64);
    if ((tid & 63) == 0) r4[tid >> 6] = part;
    __syncthreads();
    if (tid == 0) pbag[bid] = r4[0] + r4[1] + r4[2] + r4[3];
}

// -------------------------------------------------------------------------
// Kernel 3: reduce 256 bag partials per batch, BCE-with-logits mean -> out[0]
// -------------------------------------------------------------------------
__global__ __launch_bounds__(1024) void loss_kernel(
    const float* __restrict__ pbag, const float* __restrict__ labels,
    float* __restrict__ out)
{
    __shared__ float lred[32];
    const int tid = threadIdx.x;
    const int b   = tid >> 5;             // 32 batches x 32 threads
    const int j   = tid & 31;

    float s = 0.f;
    #pragma unroll
    for (int r = 0; r < 8; ++r) s += pbag[b * 256 + j + r * 32];
    #pragma unroll
    for (int k = 1; k < 32; k <<= 1) s += __shfl_xor(s, k, 64);  // stays in 32-half
    if (j == 0) {
        float x = s, y = labels[b];
        lred[b] = fmaxf(x, 0.f) - x * y + log1pf(expf(-fabsf(x)));
    }
    __syncthreads();
    if (tid < 64) {
        float l = (tid < 32) ? lred[tid] : 0.f;
        #pragma unroll
        for (int k = 1; k < 64; k <<= 1) l += __shfl_xor(l, k, 64);
        if (tid == 0) out[0] = l * (1.f / NBATCH);
    }
}

extern "C" void kernel_launch(void* const* d_in, const int* in_sizes, int n_in,
                              void* d_out, int out_size, void* d_ws, size_t ws_size,
                              hipStream_t stream)
{
    const float* logits = (const float*)d_in[0];  // (32,1,256,256)
    const float* feat   = (const float*)d_in[1];  // (32,64,256,256)
    const int*   zone   = (const int*)  d_in[2];  // (32,256,256)
    const int*   cats   = (const int*)  d_in[3];  // (32,)
    const float* labels = (const float*)d_in[4];  // (32,)
    const float* W1     = (const float*)d_in[5];  // (128,64)
    const float* b1v    = (const float*)d_in[6];  // (128,)
    const float* W2     = (const float*)d_in[7];  // (128,)
    const float* b2v    = (const float*)d_in[8];  // scalar

    float* out = (float*)d_out;       // [0] = loss, [1..] = attention_maps
    float* att = out + 1;             // reuse output buffer as score scratch

    float* wsf   = (float*)d_ws;      // 40 KB scratch; every slot rewritten
    float* pmaxb = wsf;               //  each launch before any read
    float* psumb = wsf + NBLK;        // + 1024
    float* pbag  = wsf + 2 * NBLK;    // + 8192

    mask_mlp_kernel<<<NBLK, 256, 0, stream>>>(feat, W1, b1v, W2, b2v, zone, cats,
                                              att, pmaxb, psumb);
    finalize_kernel<<<NPIX / 256, 256, 0, stream>>>(att, logits, zone, cats,
                                                    pmaxb, psumb, pbag);
    loss_kernel    <<<1, 1024, 0, stream>>>(pbag, labels, out);
}

// Round 3
// 761.096 us; speedup vs baseline: 1.4280x; 1.0254x over previous
//
#include <hip/hip_runtime.h>
#include <math.h>

#define HW       65536     // 256*256
#define NCH      64        // C
#define HIDDEN   128
#define NBATCH   32
#define NPIX     (NBATCH * HW)   // 2,097,152
#define WIN      2048            // pixels per K1 block
#define NBLK     (NPIX / WIN)    // 1024 blocks
#define WPB      (HW / WIN)      // 32 windows per batch
#define NEG_FILL -1e9f

// -------------------------------------------------------------------------
// Kernel 1: mask-compacted per-pixel MLP, online softmax partials,
// register-prefetch pipelined gather (T14 async-STAGE split).
// Each block owns a 2048-pixel window of one batch. Ballot-compacts the
// ~11% masked pixels, then per 64-pixel compacted tile:
//   write prefetched regs -> LDS; sync; ISSUE next tile's 16 scattered
//   loads into regs; run the 64x128x64 register-tiled fp32 GEMM; epilogue.
// The ~900-cycle HBM gather latency hides under the ~4.5K-cycle GEMM.
// LDS: sW 32K + sFc 16K + slist 4K ~= 52.3 KB -> 3 blocks/CU (12 waves).
// att background (unmasked px) is NEVER written here; finalize re-derives
// the mask from zone and writes 0 there.
// -------------------------------------------------------------------------
__global__ __launch_bounds__(256, 3) void mask_mlp_kernel(
    const float* __restrict__ feat,   // (B, C, H, W)
    const float* __restrict__ W1,     // (HIDDEN, C) row-major
    const float* __restrict__ b1,     // (HIDDEN)
    const float* __restrict__ W2,     // (HIDDEN)
    const float* __restrict__ b2,     // scalar
    const int*   __restrict__ zone,   // (B, H, W)
    const int*   __restrict__ cats,   // (B)
    float*       __restrict__ att,    // (B, H, W) out: scores at masked px only
    float*       __restrict__ pmax,   // (NBLK) per-window max   (-3.4e38 if none)
    float*       __restrict__ psum)   // (NBLK) per-window sum exp(x - max)
{
    __shared__ __align__(16) float sW[NCH][HIDDEN];      // sW[c][k] = W1[k][c]
    __shared__ __align__(16) float sFc[NCH][64];         // compacted feature tile
    __shared__ unsigned short slist[WIN];                // compacted local px idx
    __shared__ float sred[8];
    __shared__ int lcnt;

    const int tid  = threadIdx.x;
    const int lane = tid & 63;
    const int b    = blockIdx.x >> 5;             // WPB == 32
    const int win0 = (blockIdx.x & 31) * WIN;

    if (tid == 0) lcnt = 0;
    __syncthreads();

    // ---- stage W1 transposed (lanes walk k: conflict-free LDS stores) ----
    #pragma unroll
    for (int r = 0; r < 8; ++r) {
        int idx = tid + r * 256;      // 0..2047
        int k   = idx & 127;
        int c4  = idx >> 7;           // 0..15
        float4 v = *(const float4*)(W1 + k * NCH + c4 * 4);
        sW[c4 * 4 + 0][k] = v.x;
        sW[c4 * 4 + 1][k] = v.y;
        sW[c4 * 4 + 2][k] = v.z;
        sW[c4 * 4 + 3][k] = v.w;
    }

    // ---- scan zone, ballot-compact masked pixels (ascending order) ----
    {
        const int  catb = cats[b];
        const int* zp   = zone + (size_t)b * HW + win0;
        #pragma unroll
        for (int j = 0; j < 8; ++j) {
            int  px = j * 256 + tid;          // lanes -> consecutive pixels
            int  z  = zp[px];
            bool m  = (z == catb) && (z > 0);
            unsigned long long bal = __ballot(m);
            int rank = __popcll(bal & ((1ull << lane) - 1ull));
            int base = 0;
            if (lane == 0) {
                int cnt = __popcll(bal);
                if (cnt) base = atomicAdd(&lcnt, cnt);
            }
            base = __shfl(base, 0, 64);
            if (m) slist[base + rank] = (unsigned short)px;
        }
    }
    __syncthreads();

    const int n  = lcnt;                 // masked pixels in this window (~228)
    const int nt = (n + 63) >> 6;        // 64-pixel compacted tiles

    const int tx = tid & 15;             // hidden group: k = tx*4+j / 64+tx*4+j
    const int ty = tid >> 4;             // pixel group:  p = ty*4+i
    const int gp = tid & 63;             // gather: compacted slot lane
    const int gc = tid >> 6;             // gather: channel group (wave id)

    float b1v[8], w2v[8];
    *(float4*)&b1v[0] = *(const float4*)(b1 + tx * 4);
    *(float4*)&b1v[4] = *(const float4*)(b1 + 64 + tx * 4);
    *(float4*)&w2v[0] = *(const float4*)(W2 + tx * 4);
    *(float4*)&w2v[4] = *(const float4*)(W2 + 64 + tx * 4);
    const float b2v = b2[0];

    const float* fb = feat + (size_t)b * NCH * HW + win0;
    float*       ap = att  + (size_t)b * HW + win0;

    float mrun = -3.4e38f, srun = 0.f;   // online softmax partials

    // ---- prefetch tile 0 into registers ----
    float pv[16];
    {
        bool val = gp < n;
        int  lpx = val ? (int)slist[gp] : 0;
        const float* fp = fb + lpx;
        #pragma unroll
        for (int cc = 0; cc < 16; ++cc)
            pv[cc] = val ? fp[(size_t)(gc * 16 + cc) * HW] : 0.f;
    }

    for (int t = 0; t < nt; ++t) {
        // ---- commit prefetched tile t to LDS (conflict-free: lanes walk p) ----
        #pragma unroll
        for (int cc = 0; cc < 16; ++cc) sFc[gc * 16 + cc][gp] = pv[cc];
        __syncthreads();

        // ---- issue tile t+1's scattered loads; results land before next
        //      commit (compiler places the vmcnt wait there). GEMM below
        //      hides the ~900-cycle HBM latency. ----
        if (t + 1 < nt) {
            int  slot = (t + 1) * 64 + gp;
            bool val  = slot < n;
            int  lpx  = val ? (int)slist[slot] : 0;
            const float* fp = fb + lpx;
            #pragma unroll
            for (int cc = 0; cc < 16; ++cc)
                pv[cc] = val ? fp[(size_t)(gc * 16 + cc) * HW] : 0.f;
        }

        // ---- 64px x 128hid x 64c register-tiled GEMM ----
        float acc[4][8];
        #pragma unroll
        for (int i = 0; i < 4; ++i)
            #pragma unroll
            for (int j = 0; j < 8; ++j) acc[i][j] = 0.f;

        #pragma unroll 8
        for (int c = 0; c < NCH; ++c) {
            float a[4], w[8];
            *(float4*)&a[0] = *(const float4*)&sFc[c][ty * 4];       // broadcast
            *(float4*)&w[0] = *(const float4*)&sW[c][tx * 4];        // 2-way (free)
            *(float4*)&w[4] = *(const float4*)&sW[c][64 + tx * 4];   // 2-way (free)
            #pragma unroll
            for (int i = 0; i < 4; ++i)
                #pragma unroll
                for (int j = 0; j < 8; ++j)
                    acc[i][j] = fmaf(a[i], w[j], acc[i][j]);
        }

        // ---- epilogue: relu + W2 dot, reduce over 16 tx lanes, scatter ----
        #pragma unroll
        for (int i = 0; i < 4; ++i) {
            float s = 0.f;
            #pragma unroll
            for (int j = 0; j < 8; ++j) {
                float h = acc[i][j] + b1v[j];
                h = h > 0.f ? h : 0.f;
                s = fmaf(w2v[j], h, s);
            }
            s += __shfl_xor(s, 1, 64);
            s += __shfl_xor(s, 2, 64);
            s += __shfl_xor(s, 4, 64);
            s += __shfl_xor(s, 8, 64);
            if (tx == 0) {
                int slot = t * 64 + ty * 4 + i;
                if (slot < n) {
                    float v = s + b2v;
                    ap[slist[slot]] = v;                 // scatter score
                    float nm = fmaxf(mrun, v);           // online (m, s) update
                    srun = srun * expf(mrun - nm) + expf(v - nm);
                    mrun = nm;
                }
            }
        }
        __syncthreads();    // sFc consumed; next commit may overwrite
    }

    // ---- block-combine online (m, s) pairs -> per-window partials ----
    {
        float m = mrun, s = srun;
        #pragma unroll
        for (int k = 1; k < 64; k <<= 1) {
            float mo = __shfl_xor(m, k, 64);
            float so = __shfl_xor(s, k, 64);
            float nm = fmaxf(m, mo);
            s = s * expf(m - nm) + so * expf(mo - nm);   // finite sentinel: no NaN
            m = nm;
        }
        if (lane == 0) { sred[tid >> 6] = m; sred[4 + (tid >> 6)] = s; }
    }
    __syncthreads();
    if (tid == 0) {
        float M = sred[0], S = sred[4];
        #pragma unroll
        for (int i = 1; i < 4; ++i) {
            float mo = sred[i], so = sred[4 + i];
            float nm = fmaxf(M, mo);
            S = S * expf(M - nm) + so * expf(mo - nm);
            M = nm;
        }
        pmax[blockIdx.x] = M;
        psum[blockIdx.x] = S;
    }
}

// -------------------------------------------------------------------------
// Kernel 2: finalize. Each block (256 px of one batch) first merges the 32
// per-window partials (cheap, L2-cached), then: mask from zone, weights =
// mask&&has ? exp(score-M)/S : 0, written to att; per-block bag partial to
// pbag[blockIdx.x] -- NO atomics. Unmasked att entries were never written
// by K1 (poison); they are selected away by the mask ternary.
// -------------------------------------------------------------------------
__global__ __launch_bounds__(256) void finalize_kernel(
    float* __restrict__ att,              // in: scores at masked px, out: weights
    const float* __restrict__ logits,     // (B,1,H,W) flat
    const int*   __restrict__ zone,       // (B, H, W)
    const int*   __restrict__ cats,       // (B)
    const float* __restrict__ pmaxb, const float* __restrict__ psumb,
    float* __restrict__ pbag)             // (NPIX/256) per-block bag partials
{
    __shared__ float sM, sInv;
    __shared__ int   sHas;
    __shared__ float r4[4];

    const int bid = blockIdx.x;
    const int b   = bid >> 8;             // 256 blocks per batch
    const int tid = threadIdx.x;

    if (tid < 64) {                       // merge 32 window partials
        float m = -3.4e38f, sv = 0.f;
        if (tid < WPB) { m = pmaxb[b * WPB + tid]; sv = psumb[b * WPB + tid]; }
        float M = m;
        #pragma unroll
        for (int k = 1; k < 64; k <<= 1) M = fmaxf(M, __shfl_xor(M, k, 64));
        float z = sv * expf(m - M);       // empty windows: 0 * exp(-huge) = 0
        #pragma unroll
        for (int k = 1; k < 64; k <<= 1) z += __shfl_xor(z, k, 64);
        if (tid == 0) {
            bool has = M > -5e8f;         // any masked pixel in batch?
            sM   = M;
            sHas = has ? 1 : 0;
            sInv = has ? (1.f / z) : 0.f;
        }
    }
    __syncthreads();

    const float M   = sM;
    const float inv = sInv;
    const bool  has = sHas != 0;

    const int idx  = bid * 256 + tid;
    const int catb = cats[b];
    const int z    = zone[idx];
    const bool mk  = (z == catb) && (z > 0);

    const float a = att[idx];             // garbage at unmasked: selected away
    const float w = (mk && has) ? expf(a - M) * inv : 0.f;
    att[idx] = w;

    float part = w * logits[idx];
    #pragma unroll
    for (int s = 1; s < 64; s <<= 1) part += __shfl_xor(part, s, 64);
    if ((tid & 63) == 0) r4[tid >> 6] = part;
    __syncthreads();
    if (tid == 0) pbag[bid] = r4[0] + r4[1] + r4[2] + r4[3];
}

// -------------------------------------------------------------------------
// Kernel 3: reduce 256 bag partials per batch, BCE-with-logits mean -> out[0]
// -------------------------------------------------------------------------
__global__ __launch_bounds__(1024) void loss_kernel(
    const float* __restrict__ pbag, const float* __restrict__ labels,
    float* __restrict__ out)
{
    __shared__ float lred[32];
    const int tid = threadIdx.x;
    const int b   = tid >> 5;             // 32 batches x 32 threads
    const int j   = tid & 31;

    float s = 0.f;
    #pragma unroll
    for (int r = 0; r < 8; ++r) s += pbag[b * 256 + j + r * 32];
    #pragma unroll
    for (int k = 1; k < 32; k <<= 1) s += __shfl_xor(s, k, 64);  // stays in 32-half
    if (j == 0) {
        float x = s, y = labels[b];
        lred[b] = fmaxf(x, 0.f) - x * y + log1pf(expf(-fabsf(x)));
    }
    __syncthreads();
    if (tid < 64) {
        float l = (tid < 32) ? lred[tid] : 0.f;
        #pragma unroll
        for (int k = 1; k < 64; k <<= 1) l += __shfl_xor(l, k, 64);
        if (tid == 0) out[0] = l * (1.f / NBATCH);
    }
}

extern "C" void kernel_launch(void* const* d_in, const int* in_sizes, int n_in,
                              void* d_out, int out_size, void* d_ws, size_t ws_size,
                              hipStream_t stream)
{
    const float* logits = (const float*)d_in[0];  // (32,1,256,256)
    const float* feat   = (const float*)d_in[1];  // (32,64,256,256)
    const int*   zone   = (const int*)  d_in[2];  // (32,256,256)
    const int*   cats   = (const int*)  d_in[3];  // (32,)
    const float* labels = (const float*)d_in[4];  // (32,)
    const float* W1     = (const float*)d_in[5];  // (128,64)
    const float* b1v    = (const float*)d_in[6];  // (128,)
    const float* W2     = (const float*)d_in[7];  // (128,)
    const float* b2v    = (const float*)d_in[8];  // scalar

    float* out = (float*)d_out;       // [0] = loss, [1..] = attention_maps
    float* att = out + 1;             // reuse output buffer as score scratch

    float* wsf   = (float*)d_ws;      // 40 KB scratch; every slot rewritten
    float* pmaxb = wsf;               //  each launch before any read
    float* psumb = wsf + NBLK;        // + 1024
    float* pbag  = wsf + 2 * NBLK;    // + 8192

    mask_mlp_kernel<<<NBLK, 256, 0, stream>>>(feat, W1, b1v, W2, b2v, zone, cats,
                                              att, pmaxb, psumb);
    finalize_kernel<<<NPIX / 256, 256, 0, stream>>>(att, logits, zone, cats,
                                                    pmaxb, psumb, pbag);
    loss_kernel    <<<1, 1024, 0, stream>>>(pbag, labels, out);
}

// Round 4
// 752.987 us; speedup vs baseline: 1.4433x; 1.0108x over previous
//
#include <hip/hip_runtime.h>
#include <math.h>

#define HW       65536     // 256*256
#define NCH      64        // C
#define HIDDEN   128
#define NBATCH   32
#define NPIX     (NBATCH * HW)   // 2,097,152
#define WIN      2048            // pixels per K1 block
#define NBLK     (NPIX / WIN)    // 1024 blocks
#define WPB      (HW / WIN)      // 32 windows per batch
#define NEG_FILL -1e9f

// -------------------------------------------------------------------------
// Kernel 1: mask-compacted per-pixel MLP, online softmax partials,
// register-prefetch pipelined gather (T14 issue-early / write-late).
// Changes vs prev round:
//  (a) gather loads are UNCONDITIONAL (out-of-range slots clamp to the last
//      valid compacted pixel) -> no v_cndmask consumes the load results at
//      the issue site, so the vmcnt wait sinks to the next tile's LDS
//      commit, and the ~900-cycle HBM latency hides under the GEMM.
//      Previous round's `val ? load : 0` select forced the wait BEFORE the
//      GEMM - the pipeline never engaged (total only moved -19us).
//  (b) compaction is globally ASCENDING (2-phase ballot count + prefix sum
//      instead of atomicAdd round-interleave) -> a gather wave's 64 lanes
//      walk ascending addresses (~36 sequential 64B lines per instr):
//      proper coalescing + near-streaming DRAM order.
// LDS: sW 32K + sFc 16K + slist 4K ~= 52.4 KB -> 3 blocks/CU (12 waves).
// -------------------------------------------------------------------------
__global__ __launch_bounds__(256, 3) void mask_mlp_kernel(
    const float* __restrict__ feat,   // (B, C, H, W)
    const float* __restrict__ W1,     // (HIDDEN, C) row-major
    const float* __restrict__ b1,     // (HIDDEN)
    const float* __restrict__ W2,     // (HIDDEN)
    const float* __restrict__ b2,     // scalar
    const int*   __restrict__ zone,   // (B, H, W)
    const int*   __restrict__ cats,   // (B)
    float*       __restrict__ att,    // (B, H, W) out: scores at masked px only
    float*       __restrict__ pmax,   // (NBLK) per-window max   (-3.4e38 if none)
    float*       __restrict__ psum)   // (NBLK) per-window sum exp(x - max)
{
    __shared__ __align__(16) float sW[NCH][HIDDEN];      // sW[c][k] = W1[k][c]
    __shared__ __align__(16) float sFc[NCH][64];         // compacted feature tile
    __shared__ unsigned short slist[WIN];                // compacted local px idx
    __shared__ float sred[8];
    __shared__ int   scnt[33];                           // 32 group counts + total

    const int tid  = threadIdx.x;
    const int lane = tid & 63;
    const int wid  = tid >> 6;
    const int b    = blockIdx.x >> 5;             // WPB == 32
    const int win0 = (blockIdx.x & 31) * WIN;

    // ---- stage W1 transposed (lanes walk k: conflict-free LDS stores) ----
    #pragma unroll
    for (int r = 0; r < 8; ++r) {
        int idx = tid + r * 256;      // 0..2047
        int k   = idx & 127;
        int c4  = idx >> 7;           // 0..15
        float4 v = *(const float4*)(W1 + k * NCH + c4 * 4);
        sW[c4 * 4 + 0][k] = v.x;
        sW[c4 * 4 + 1][k] = v.y;
        sW[c4 * 4 + 2][k] = v.z;
        sW[c4 * 4 + 3][k] = v.w;
    }

    // ---- phase 1: per-(round, wave) mask counts ----
    const int  catb = cats[b];
    const int* zp   = zone + (size_t)b * HW + win0;
    int zv[8];
    #pragma unroll
    for (int j = 0; j < 8; ++j) {
        zv[j] = zp[j * 256 + tid];                // px = j*256 + tid (ascending)
        bool m = (zv[j] == catb) && (zv[j] > 0);
        unsigned long long bal = __ballot(m);
        if (lane == 0) scnt[j * 4 + wid] = __popcll(bal);
    }
    __syncthreads();

    // ---- phase 2: serial prefix over the 32 group counts ----
    if (tid == 0) {
        int a = 0;
        #pragma unroll
        for (int i = 0; i < 32; ++i) { int c = scnt[i]; scnt[i] = a; a += c; }
        scnt[32] = a;
    }
    __syncthreads();

    // ---- phase 3: ranked writes -> globally ascending slist ----
    #pragma unroll
    for (int j = 0; j < 8; ++j) {
        bool m = (zv[j] == catb) && (zv[j] > 0);
        unsigned long long bal = __ballot(m);
        int rank = __popcll(bal & ((1ull << lane) - 1ull));
        if (m) slist[scnt[j * 4 + wid] + rank] = (unsigned short)(j * 256 + tid);
    }
    __syncthreads();

    const int n  = scnt[32];             // masked pixels in this window (~228)
    const int nt = (n + 63) >> 6;        // 64-pixel compacted tiles

    const int tx = tid & 15;             // hidden group: k = tx*4+j / 64+tx*4+j
    const int ty = tid >> 4;             // pixel group:  p = ty*4+i
    const int gp = tid & 63;             // gather: compacted slot lane
    const int gc = tid >> 6;             // gather: channel group (wave id)

    float b1v[8], w2v[8];
    *(float4*)&b1v[0] = *(const float4*)(b1 + tx * 4);
    *(float4*)&b1v[4] = *(const float4*)(b1 + 64 + tx * 4);
    *(float4*)&w2v[0] = *(const float4*)(W2 + tx * 4);
    *(float4*)&w2v[4] = *(const float4*)(W2 + 64 + tx * 4);
    const float b2v = b2[0];

    const float* fb = feat + (size_t)b * NCH * HW + win0;
    float*       ap = att  + (size_t)b * HW + win0;

    float mrun = -3.4e38f, srun = 0.f;   // online softmax partials

    // ---- prologue: prefetch tile 0 (unconditional, clamped index) ----
    float pv[16];
    if (n > 0) {
        int cs = gp < n ? gp : n - 1;    // clamp: redundant load of a valid px
        const float* fp = fb + (int)slist[cs];
        #pragma unroll
        for (int cc = 0; cc < 16; ++cc)
            pv[cc] = fp[(size_t)(gc * 16 + cc) * HW];
    }

    for (int t = 0; t < nt; ++t) {
        // ---- commit prefetched tile t to LDS (vmcnt wait lands HERE,
        //      after the previous iteration's GEMM) ----
        #pragma unroll
        for (int cc = 0; cc < 16; ++cc) sFc[gc * 16 + cc][gp] = pv[cc];
        __syncthreads();

        // ---- issue tile t+1's loads: NO consumer until next commit ----
        if (t + 1 < nt) {
            int slot = (t + 1) * 64 + gp;
            int cs   = slot < n ? slot : n - 1;
            const float* fp = fb + (int)slist[cs];
            #pragma unroll
            for (int cc = 0; cc < 16; ++cc)
                pv[cc] = fp[(size_t)(gc * 16 + cc) * HW];
        }

        // ---- 64px x 128hid x 64c register-tiled GEMM (hides the gather) ----
        float acc[4][8];
        #pragma unroll
        for (int i = 0; i < 4; ++i)
            #pragma unroll
            for (int j = 0; j < 8; ++j) acc[i][j] = 0.f;

        #pragma unroll 8
        for (int c = 0; c < NCH; ++c) {
            float a[4], w[8];
            *(float4*)&a[0] = *(const float4*)&sFc[c][ty * 4];       // broadcast
            *(float4*)&w[0] = *(const float4*)&sW[c][tx * 4];        // 2-way (free)
            *(float4*)&w[4] = *(const float4*)&sW[c][64 + tx * 4];   // 2-way (free)
            #pragma unroll
            for (int i = 0; i < 4; ++i)
                #pragma unroll
                for (int j = 0; j < 8; ++j)
                    acc[i][j] = fmaf(a[i], w[j], acc[i][j]);
        }
        // note: columns with slot >= n hold garbage (clamped loads from a
        // valid pixel) - column-isolated, discarded by the slot<n guards.

        // ---- epilogue: relu + W2 dot, reduce over 16 tx lanes, scatter ----
        #pragma unroll
        for (int i = 0; i < 4; ++i) {
            float s = 0.f;
            #pragma unroll
            for (int j = 0; j < 8; ++j) {
                float h = acc[i][j] + b1v[j];
                h = h > 0.f ? h : 0.f;
                s = fmaf(w2v[j], h, s);
            }
            s += __shfl_xor(s, 1, 64);
            s += __shfl_xor(s, 2, 64);
            s += __shfl_xor(s, 4, 64);
            s += __shfl_xor(s, 8, 64);
            if (tx == 0) {
                int slot = t * 64 + ty * 4 + i;
                if (slot < n) {
                    float v = s + b2v;
                    ap[slist[slot]] = v;                 // scatter score
                    float nm = fmaxf(mrun, v);           // online (m, s) update
                    srun = srun * expf(mrun - nm) + expf(v - nm);
                    mrun = nm;
                }
            }
        }
        __syncthreads();    // sFc consumed; next commit may overwrite
    }

    // ---- block-combine online (m, s) pairs -> per-window partials ----
    {
        float m = mrun, s = srun;
        #pragma unroll
        for (int k = 1; k < 64; k <<= 1) {
            float mo = __shfl_xor(m, k, 64);
            float so = __shfl_xor(s, k, 64);
            float nm = fmaxf(m, mo);
            s = s * expf(m - nm) + so * expf(mo - nm);   // finite sentinel: no NaN
            m = nm;
        }
        if (lane == 0) { sred[wid] = m; sred[4 + wid] = s; }
    }
    __syncthreads();
    if (tid == 0) {
        float M = sred[0], S = sred[4];
        #pragma unroll
        for (int i = 1; i < 4; ++i) {
            float mo = sred[i], so = sred[4 + i];
            float nm = fmaxf(M, mo);
            S = S * expf(M - nm) + so * expf(mo - nm);
            M = nm;
        }
        pmax[blockIdx.x] = M;
        psum[blockIdx.x] = S;
    }
}

// -------------------------------------------------------------------------
// Kernel 2: finalize. Each block (256 px of one batch) first merges the 32
// per-window partials (cheap, L2-cached), then: mask from zone, weights =
// mask&&has ? exp(score-M)/S : 0, written to att; per-block bag partial to
// pbag[blockIdx.x] -- NO atomics. Unmasked att entries were never written
// by K1 (poison); they are selected away by the mask ternary.
// -------------------------------------------------------------------------
__global__ __launch_bounds__(256) void finalize_kernel(
    float* __restrict__ att,              // in: scores at masked px, out: weights
    const float* __restrict__ logits,     // (B,1,H,W) flat
    const int*   __restrict__ zone,       // (B, H, W)
    const int*   __restrict__ cats,       // (B)
    const float* __restrict__ pmaxb, const float* __restrict__ psumb,
    float* __restrict__ pbag)             // (NPIX/256) per-block bag partials
{
    __shared__ float sM, sInv;
    __shared__ int   sHas;
    __shared__ float r4[4];

    const int bid = blockIdx.x;
    const int b   = bid >> 8;             // 256 blocks per batch
    const int tid = threadIdx.x;

    if (tid < 64) {                       // merge 32 window partials
        float m = -3.4e38f, sv = 0.f;
        if (tid < WPB) { m = pmaxb[b * WPB + tid]; sv = psumb[b * WPB + tid]; }
        float M = m;
        #pragma unroll
        for (int k = 1; k < 64; k <<= 1) M = fmaxf(M, __shfl_xor(M, k, 64));
        float z = sv * expf(m - M);       // empty windows: 0 * exp(-huge) = 0
        #pragma unroll
        for (int k = 1; k < 64; k <<= 1) z += __shfl_xor(z, k, 64);
        if (tid == 0) {
            bool has = M > -5e8f;         // any masked pixel in batch?
            sM   = M;
            sHas = has ? 1 : 0;
            sInv = has ? (1.f / z) : 0.f;
        }
    }
    __syncthreads();

    const float M   = sM;
    const float inv = sInv;
    const bool  has = sHas != 0;

    const int idx  = bid * 256 + tid;
    const int catb = cats[b];
    const int z    = zone[idx];
    const bool mk  = (z == catb) && (z > 0);

    const float a = att[idx];             // garbage at unmasked: selected away
    const float w = (mk && has) ? expf(a - M) * inv : 0.f;
    att[idx] = w;

    float part = w * logits[idx];
    #pragma unroll
    for (int s = 1; s < 64; s <<= 1) part += __shfl_xor(part, s, 64);
    if ((tid & 63) == 0) r4[tid >> 6] = part;
    __syncthreads();
    if (tid == 0) pbag[bid] = r4[0] + r4[1] + r4[2] + r4[3];
}

// -------------------------------------------------------------------------
// Kernel 3: reduce 256 bag partials per batch, BCE-with-logits mean -> out[0]
// -------------------------------------------------------------------------
__global__ __launch_bounds__(1024) void loss_kernel(
    const float* __restrict__ pbag, const float* __restrict__ labels,
    float* __restrict__ out)
{
    __shared__ float lred[32];
    const int tid = threadIdx.x;
    const int b   = tid >> 5;             // 32 batches x 32 threads
    const int j   = tid & 31;

    float s = 0.f;
    #pragma unroll
    for (int r = 0; r < 8; ++r) s += pbag[b * 256 + j + r * 32];
    #pragma unroll
    for (int k = 1; k < 32; k <<= 1) s += __shfl_xor(s, k, 64);  // stays in 32-half
    if (j == 0) {
        float x = s, y = labels[b];
        lred[b] = fmaxf(x, 0.f) - x * y + log1pf(expf(-fabsf(x)));
    }
    __syncthreads();
    if (tid < 64) {
        float l = (tid < 32) ? lred[tid] : 0.f;
        #pragma unroll
        for (int k = 1; k < 64; k <<= 1) l += __shfl_xor(l, k, 64);
        if (tid == 0) out[0] = l * (1.f / NBATCH);
    }
}

extern "C" void kernel_launch(void* const* d_in, const int* in_sizes, int n_in,
                              void* d_out, int out_size, void* d_ws, size_t ws_size,
                              hipStream_t stream)
{
    const float* logits = (const float*)d_in[0];  // (32,1,256,256)
    const float* feat   = (const float*)d_in[1];  // (32,64,256,256)
    const int*   zone   = (const int*)  d_in[2];  // (32,256,256)
    const int*   cats   = (const int*)  d_in[3];  // (32,)
    const float* labels = (const float*)d_in[4];  // (32,)
    const float* W1     = (const float*)d_in[5];  // (128,64)
    const float* b1v    = (const float*)d_in[6];  // (128,)
    const float* W2     = (const float*)d_in[7];  // (128,)
    const float* b2v    = (const float*)d_in[8];  // scalar

    float* out = (float*)d_out;       // [0] = loss, [1..] = attention_maps
    float* att = out + 1;             // reuse output buffer as score scratch

    float* wsf   = (float*)d_ws;      // 40 KB scratch; every slot rewritten
    float* pmaxb = wsf;               //  each launch before any read
    float* psumb = wsf + NBLK;        // + 1024
    float* pbag  = wsf + 2 * NBLK;    // + 8192

    mask_mlp_kernel<<<NBLK, 256, 0, stream>>>(feat, W1, b1v, W2, b2v, zone, cats,
                                              att, pmaxb, psumb);
    finalize_kernel<<<NPIX / 256, 256, 0, stream>>>(att, logits, zone, cats,
                                                    pmaxb, psumb, pbag);
    loss_kernel    <<<1, 1024, 0, stream>>>(pbag, labels, out);
}